// Round 1
// 220.397 us; speedup vs baseline: 1.1544x; 1.1544x over previous
//
#include <hip/hip_runtime.h>

#define TLEN 4096
#define DIM 1024
#define NHEAD 16
#define HDIM 64
#define QKV_COLS (3 * DIM)
// 0.125 * log2(e): attention scores computed in exp2 domain (v_exp_f32 is 2^x)
#define QSCALE 0.1803368801111244f
#define NCHUNK 2
#define SCHUNK (TLEN / NCHUNK)
#define TB 256   // t rows per attn block (wave owns 64 t = 4 strips of 16)

typedef __attribute__((ext_vector_type(8))) short short8;   // 8 bf16 = 4 VGPR (MFMA A/B frag)
typedef __attribute__((ext_vector_type(4))) float f32x4;    // MFMA C/D frag

struct alignas(8) s4 { short v[4]; };

__device__ float g_Lsum[NHEAD];
__device__ float g_recipL[NHEAD];

__global__ void zeroL() {
    if (threadIdx.x < NHEAD) g_Lsum[threadIdx.x] = 0.0f;
}
__global__ void recipL() {
    if (threadIdx.x < NHEAD) g_recipL[threadIdx.x] = 1.0f / g_Lsum[threadIdx.x];
}

__device__ __forceinline__ unsigned bf16_rtne_bits(float x) {
    unsigned u = __float_as_uint(x);
    return (u + 0x7fffu + ((u >> 16) & 1u)) >> 16;
}

// async global->LDS 16B copy (global_load_lds_dwordx4). LDS dest must be
// wave-uniform base + lane*16 at the callsite (our staging layouts are).
__device__ __forceinline__ void cp16(const short* g, short* l) {
    __builtin_amdgcn_global_load_lds(
        (const __attribute__((address_space(1))) unsigned int*)g,
        (__attribute__((address_space(3))) unsigned int*)l,
        16, 0, 0);
}

__device__ __forceinline__ short8 mk8(unsigned a, unsigned b, unsigned c, unsigned d) {
    union { unsigned u[4]; short8 s; } t;
    t.u[0] = a; t.u[1] = b; t.u[2] = c; t.u[3] = d;
    return t.s;
}

// fp32 -> bf16 (RTNE), vectorized; n4 = element count / 4.
__global__ __launch_bounds__(256) void conv_bf16(
    const float* __restrict__ src, short* __restrict__ dst, int n4)
{
    int i = blockIdx.x * 256 + threadIdx.x;
    if (i < n4) {
        float4 v = ((const float4*)src)[i];
        s4 o;
        o.v[0] = (short)bf16_rtne_bits(v.x);
        o.v[1] = (short)bf16_rtne_bits(v.y);
        o.v[2] = (short)bf16_rtne_bits(v.z);
        o.v[3] = (short)bf16_rtne_bits(v.w);
        ((s4*)dst)[i] = o;
    }
}

// W_out [1024,1024] -> bf16 with per-head 1/L folded in (k-group = k/64).
__global__ __launch_bounds__(256) void conv_wout(
    const float* __restrict__ src, short* __restrict__ dst)
{
    int i = blockIdx.x * 256 + threadIdx.x;   // over 1024*1024/4
    float s = g_recipL[(i & 255) >> 4];       // k = (i&255)*4; head = k>>6
    float4 v = ((const float4*)src)[i];
    s4 o;
    o.v[0] = (short)bf16_rtne_bits(v.x * s);
    o.v[1] = (short)bf16_rtne_bits(v.y * s);
    o.v[2] = (short)bf16_rtne_bits(v.z * s);
    o.v[3] = (short)bf16_rtne_bits(v.w * s);
    ((s4*)dst)[i] = o;
}

// attnb = bf16(part0 + part1); n4 = elements/4.
__global__ __launch_bounds__(256) void combine(
    const short* __restrict__ p0, const short* __restrict__ p1,
    short* __restrict__ dst, int n4)
{
    int i = blockIdx.x * 256 + threadIdx.x;
    if (i < n4) {
        s4 a = ((const s4*)p0)[i];
        s4 b = ((const s4*)p1)[i];
        s4 o;
#pragma unroll
        for (int m = 0; m < 4; ++m) {
            float fa = __uint_as_float(((unsigned)(unsigned short)a.v[m]) << 16);
            float fb = __uint_as_float(((unsigned)(unsigned short)b.v[m]) << 16);
            o.v[m] = (short)bf16_rtne_bits(fa + fb);
        }
        ((s4*)dst)[i] = o;
    }
}

// C = A @ B^T, bf16 MFMA. 128x128 tile, 4 waves 2x2, BK=32.
// Staging via async global_load_lds width=16.
// QKV_MODE: bf16 out; Q cols (n<DIM) scaled by QSCALE; V cols (n>=2*DIM)
//   written TRANSPOSED to Vout[d_global][t] as packed uint2.
// else: fp32 out to Cout.
template <bool QKV_MODE>
__global__ __launch_bounds__(256) void gemm_bt(
    const short* __restrict__ A, const short* __restrict__ B,
    void* __restrict__ Cout, short* __restrict__ Vout, int M, int N, int K)
{
    __shared__ __align__(16) short As[128][32];
    __shared__ __align__(16) short Bs[128][32];
    const int tid  = threadIdx.x;
    const int wv   = tid >> 6, lane = tid & 63;
    const int fr   = lane & 15, quad = lane >> 4;
    const int wm   = (wv >> 1) * 64, wn = (wv & 1) * 64;
    const int m0 = blockIdx.x * 128, n0 = blockIdx.y * 128;

    f32x4 acc[4][4] = {};

    for (int k0 = 0; k0 < K; k0 += 32) {
        __syncthreads();
#pragma unroll
        for (int c = tid; c < 512; c += 256) {
            int row = c >> 2, col = (c & 3) * 8;
            cp16(A + (size_t)(m0 + row) * K + k0 + col, &As[row][col]);
            cp16(B + (size_t)(n0 + row) * K + k0 + col, &Bs[row][col]);
        }
        __syncthreads();   // drains vmcnt (async LDS stores) before reads

        short8 af[4], bfr[4];
#pragma unroll
        for (int i = 0; i < 4; ++i) {
            af[i]  = *(const short8*)&As[wm + i * 16 + fr][quad * 8];
            bfr[i] = *(const short8*)&Bs[wn + i * 16 + fr][quad * 8];
        }
#pragma unroll
        for (int i = 0; i < 4; ++i)
#pragma unroll
            for (int j = 0; j < 4; ++j)
                acc[i][j] = __builtin_amdgcn_mfma_f32_16x16x32_bf16(af[i], bfr[j], acc[i][j], 0, 0, 0);
    }

    if (QKV_MODE && n0 >= 2 * DIM) {
        // V tile: write V^T[d_global][t], packed 4 consecutive t per lane
#pragma unroll
        for (int i = 0; i < 4; ++i)
#pragma unroll
            for (int j = 0; j < 4; ++j) {
                int n = n0 - 2 * DIM + wn + j * 16 + fr;        // d_global
                int m = m0 + wm + i * 16 + quad * 4;            // t base
                unsigned u0 = bf16_rtne_bits(acc[i][j][0]);
                unsigned u1 = bf16_rtne_bits(acc[i][j][1]);
                unsigned u2 = bf16_rtne_bits(acc[i][j][2]);
                unsigned u3 = bf16_rtne_bits(acc[i][j][3]);
                uint2 pk;
                pk.x = u0 | (u1 << 16);
                pk.y = u2 | (u3 << 16);
                *(uint2*)(Vout + (size_t)n * TLEN + m) = pk;
            }
    } else if (QKV_MODE) {
        const float sc = (n0 < DIM) ? QSCALE : 1.0f;
#pragma unroll
        for (int i = 0; i < 4; ++i)
#pragma unroll
            for (int j = 0; j < 4; ++j)
#pragma unroll
                for (int r = 0; r < 4; ++r) {
                    size_t off = (size_t)(m0 + wm + i * 16 + quad * 4 + r) * N + n0 + wn + j * 16 + fr;
                    ((short*)Cout)[off] = (short)bf16_rtne_bits(acc[i][j][r] * sc);
                }
    } else {
#pragma unroll
        for (int i = 0; i < 4; ++i)
#pragma unroll
            for (int j = 0; j < 4; ++j)
#pragma unroll
                for (int r = 0; r < 4; ++r) {
                    size_t off = (size_t)(m0 + wm + i * 16 + quad * 4 + r) * N + n0 + wn + j * 16 + fr;
                    ((float*)Cout)[off] = acc[i][j][r];
                }
    }
}

// LDS-staged attention, 256-t tile, P kept IN REGISTERS.
//  - S^T = K.Q^T per 16-t strip; exp2 + trunc-pack to bf16 pairs (v_perm)
//  - P^T->PV-B-fragment redistribution via 2x permlane32_swap + 2x
//    permlane16_swap per (strip, pair): dst(q1,q0) <- src(q0,s0), i=2kh+q1.
//    No Ps LDS buffer, no scatter writes, no read-back.
//  - K/V fragments read once per s-tile, reused across 4 t-strips
//  - next s-tile K/V global loads issued right after the barrier (latency
//    hides under compute); Q loaded straight into registers at kernel start
__global__ __launch_bounds__(256, 2) void attn_mfma(
    const short* __restrict__ qkvb, const short* __restrict__ vtb,
    short* __restrict__ part)
{
    __shared__ __align__(16) short Ks[64][72];    // [s][d]
    __shared__ __align__(16) short Vt[64][72];    // [d][s]
    __shared__ float red[256];

    const int tid = threadIdx.x;
    const int t0 = blockIdx.x * TB;
    const int h  = blockIdx.y;
    const int chunk = blockIdx.z;
    const int srow = tid >> 2;          // 0..63 staging row
    const int sch  = (tid & 3) * 16;    // 0,16,32,48 staging col chunk
    const int wv   = tid >> 6;
    const int lane = tid & 63;
    const int fr   = lane & 15;
    const int quad = lane >> 4;
    const int tb   = wv * 64;           // wave's t-strip base within the tile

    // ---- Q fragments (B-operand) direct from global: 4 strips x 2 k-halves
    short8 qf[4][2];
#pragma unroll
    for (int jt = 0; jt < 4; ++jt) {
        const short* qsrc = qkvb + (size_t)(t0 + tb + jt * 16 + fr) * QKV_COLS + h * HDIM + quad * 8;
        qf[jt][0] = *(const short8*)qsrc;
        qf[jt][1] = *(const short8*)(qsrc + 32);
    }

    short8 ones;
#pragma unroll
    for (int m = 0; m < 8; ++m) ones[m] = (short)0x3F80;   // bf16 1.0

    f32x4 oaccT[4][4] = {};   // [jd][jt], O^T[d][t]
    f32x4 racc[4] = {};       // P column sums per jt (quad-duplicated)

    const int s_begin = chunk * SCHUNK;
    const short* kbase = qkvb + DIM + h * HDIM + sch;
    const short* vbase = vtb + (size_t)(h * HDIM + srow) * TLEN + sch;

    // prologue: stage first s-tile into registers
    uint4 kA, kB, vA, vB;
    {
        const short* ks = kbase + (size_t)(s_begin + srow) * QKV_COLS;
        kA = *(const uint4*)ks;  kB = *(const uint4*)(ks + 8);
        const short* vs = vbase + s_begin;
        vA = *(const uint4*)vs;  vB = *(const uint4*)(vs + 8);
    }

    for (int it = 0; it < SCHUNK / 64; ++it) {
        *(uint4*)&Ks[srow][sch]     = kA;
        *(uint4*)&Ks[srow][sch + 8] = kB;
        *(uint4*)&Vt[srow][sch]     = vA;
        *(uint4*)&Vt[srow][sch + 8] = vB;
        __syncthreads();

        // issue next-tile loads now; latency hides under this tile's compute
        if (it + 1 < SCHUNK / 64) {
            const int s0n = s_begin + (it + 1) * 64;
            const short* ks = kbase + (size_t)(s0n + srow) * QKV_COLS;
            kA = *(const uint4*)ks;  kB = *(const uint4*)(ks + 8);
            const short* vs = vbase + s0n;
            vA = *(const uint4*)vs;  vB = *(const uint4*)(vs + 8);
        }

        // K and V fragments for this s-tile (reused across all 4 t-strips)
        short8 kf[4][2], vf[4][2];
#pragma unroll
        for (int i = 0; i < 4; ++i) {
            kf[i][0] = *(const short8*)&Ks[i * 16 + fr][quad * 8];
            kf[i][1] = *(const short8*)&Ks[i * 16 + fr][32 + quad * 8];
            vf[i][0] = *(const short8*)&Vt[i * 16 + fr][quad * 8];
            vf[i][1] = *(const short8*)&Vt[i * 16 + fr][32 + quad * 8];
        }

#pragma unroll
        for (int jt = 0; jt < 4; ++jt) {
            // S^T = K.Q^T: lane holds s = i*16+quad*4+r, t = tb+jt*16+fr
            unsigned w0[4], w1[4];   // w[i][p]: bf16 pair for s = i*16+quad*4+2p,+1
#pragma unroll
            for (int i = 0; i < 4; ++i) {
                f32x4 acc = {};
                acc = __builtin_amdgcn_mfma_f32_16x16x32_bf16(kf[i][0], qf[jt][0], acc, 0, 0, 0);
                acc = __builtin_amdgcn_mfma_f32_16x16x32_bf16(kf[i][1], qf[jt][1], acc, 0, 0, 0);
                unsigned u0 = __float_as_uint(__builtin_amdgcn_exp2f(acc[0]));
                unsigned u1 = __float_as_uint(__builtin_amdgcn_exp2f(acc[1]));
                unsigned u2 = __float_as_uint(__builtin_amdgcn_exp2f(acc[2]));
                unsigned u3 = __float_as_uint(__builtin_amdgcn_exp2f(acc[3]));
                w0[i] = __builtin_amdgcn_perm(u1, u0, 0x07060302);  // trunc-pack
                w1[i] = __builtin_amdgcn_perm(u3, u2, 0x07060302);
            }
            // in-register redistribution to PV B-fragment layout:
            //   after pl32swap(w[2k],w[2k+1]):  a0 = w[q1]@src(0,q0), a1 = w[q1]@src(1,q0)
            //   after pl16swap(a0,a1):          o0 = w[q1]@src(q0,0), o1 = w[q1]@src(q0,1)
            auto A0 = __builtin_amdgcn_permlane32_swap(w0[0], w0[1], false, false);
            auto A2 = __builtin_amdgcn_permlane32_swap(w0[2], w0[3], false, false);
            auto B0 = __builtin_amdgcn_permlane32_swap(w1[0], w1[1], false, false);
            auto B2 = __builtin_amdgcn_permlane32_swap(w1[2], w1[3], false, false);
            auto O0 = __builtin_amdgcn_permlane16_swap(A0[0], A0[1], false, false);
            auto O2 = __builtin_amdgcn_permlane16_swap(A2[0], A2[1], false, false);
            auto P0 = __builtin_amdgcn_permlane16_swap(B0[0], B0[1], false, false);
            auto P2 = __builtin_amdgcn_permlane16_swap(B2[0], B2[1], false, false);
            short8 pb0 = mk8(O0[0], P0[0], O0[1], P0[1]);   // kh=0: s = quad*8+0..7
            short8 pb1 = mk8(O2[0], P2[0], O2[1], P2[1]);   // kh=1: s = 32+quad*8+0..7

            // P column sums via ones-row MFMA (sums the truncated P exactly)
            racc[jt] = __builtin_amdgcn_mfma_f32_16x16x32_bf16(ones, pb0, racc[jt], 0, 0, 0);
            racc[jt] = __builtin_amdgcn_mfma_f32_16x16x32_bf16(ones, pb1, racc[jt], 0, 0, 0);

            // O^T += V^T.P
#pragma unroll
            for (int jd = 0; jd < 4; ++jd) {
                oaccT[jd][jt] = __builtin_amdgcn_mfma_f32_16x16x32_bf16(vf[jd][0], pb0, oaccT[jd][jt], 0, 0, 0);
                oaccT[jd][jt] = __builtin_amdgcn_mfma_f32_16x16x32_bf16(vf[jd][1], pb1, oaccT[jd][jt], 0, 0, 0);
            }
        }
        __syncthreads();   // all waves done reading Ks/Vt before next overwrite
    }

    // ---- epilogue: O^T[d][t] -> part[chunk][t][h*64+d], bf16, b64 stores ----
    short* pc = part + (size_t)chunk * TLEN * DIM;
#pragma unroll
    for (int jt = 0; jt < 4; ++jt)
#pragma unroll
        for (int jd = 0; jd < 4; ++jd) {
            unsigned u0 = bf16_rtne_bits(oaccT[jd][jt][0]);
            unsigned u1 = bf16_rtne_bits(oaccT[jd][jt][1]);
            unsigned u2 = bf16_rtne_bits(oaccT[jd][jt][2]);
            unsigned u3 = bf16_rtne_bits(oaccT[jd][jt][3]);
            uint2 pk;
            pk.x = u0 | (u1 << 16);
            pk.y = u2 | (u3 << 16);
            *(uint2*)(pc + (size_t)(t0 + tb + jt * 16 + fr) * DIM + h * HDIM + jd * 16 + quad * 4) = pk;
        }

    // ---- block-reduce L, one atomic per block (racc quad-duplicated /4) ----
    red[tid] = (racc[0][0] + racc[1][0] + racc[2][0] + racc[3][0]) * 0.25f;
    __syncthreads();
    for (int off = 128; off > 0; off >>= 1) {
        if (tid < off) red[tid] += red[tid + off];
        __syncthreads();
    }
    if (tid == 0) atomicAdd(&g_Lsum[h], red[0]);
}

extern "C" void kernel_launch(void* const* d_in, const int* in_sizes, int n_in,
                              void* d_out, int out_size, void* d_ws, size_t ws_size,
                              hipStream_t stream)
{
    const float* x     = (const float*)d_in[0];   // [4096, 1024]
    const float* W_in  = (const float*)d_in[1];   // [3072, 1024]
    const float* W_out = (const float*)d_in[2];   // [1024, 1024]
    float* out = (float*)d_out;                   // [4096, 1024] fp32

    char* ws = (char*)d_ws;
    short* xb    = (short*)(ws);                   //  8 MiB @ 0   (later: attnb)
    short* wib   = (short*)(ws + (8u << 20));      //  6 MiB @ 8M
    short* wob   = (short*)(ws + (14u << 20));     //  2 MiB @ 14M
    short* qkvb  = (short*)(ws + (16u << 20));     // 24 MiB @ 16M (V region unused)
    short* vtb   = (short*)(ws + (40u << 20));     //  8 MiB @ 40M (V^T [d_global][s])
    short* part  = (short*)(ws + (48u << 20));     // 16 MiB @ 48M (2 chunks x 8 MiB)
    short* attnb = xb;                             // reuse dead xb region
    // total: exactly 64 MiB (proven safe in R3/R4)

    zeroL<<<1, 64, 0, stream>>>();

    conv_bf16<<<(TLEN * DIM / 4 + 255) / 256, 256, 0, stream>>>(x, xb, TLEN * DIM / 4);
    conv_bf16<<<(QKV_COLS * DIM / 4 + 255) / 256, 256, 0, stream>>>(W_in, wib, QKV_COLS * DIM / 4);

    // qkv = x @ W_in^T  (bf16 MFMA; Q cols x0.125*log2e; V cols -> vtb transposed)
    gemm_bt<true><<<dim3(TLEN / 128, QKV_COLS / 128), 256, 0, stream>>>(
        xb, wib, qkvb, vtb, TLEN, QKV_COLS, DIM);

    attn_mfma<<<dim3(TLEN / TB, NHEAD, NCHUNK), 256, 0, stream>>>(qkvb, vtb, part);

    recipL<<<1, 64, 0, stream>>>();
    conv_wout<<<(DIM * DIM / 4 + 255) / 256, 256, 0, stream>>>(W_out, wob);

    combine<<<(TLEN * DIM / 4 + 255) / 256, 256, 0, stream>>>(
        part, part + (size_t)TLEN * DIM, attnb, TLEN * DIM / 4);

    // out = attn' @ (W_out/L)^T  (bf16 MFMA, fp32 out)
    gemm_bt<false><<<dim3(TLEN / 128, DIM / 128), 256, 0, stream>>>(
        attnb, wob, out, nullptr, TLEN, DIM, DIM);
}